// Round 1
// baseline (98.302 us; speedup 1.0000x reference)
//
#include <hip/hip_runtime.h>
#include <stdint.h>

#define N_TOK 16384
#define F_DIM 128
#define U_DIM 64
#define E_DIM 32
#define MT    64

typedef __bf16 bf16x8 __attribute__((ext_vector_type(8)));
typedef float  floatx4 __attribute__((ext_vector_type(4)));

#define MFMA16(a, b, c) __builtin_amdgcn_mfma_f32_16x16x32_bf16((a), (b), (c), 0, 0, 0)

__device__ __forceinline__ unsigned short f2bf(float f) {
  union { float f; unsigned u; } v; v.f = f;
  unsigned r = v.u + 0x7FFFu + ((v.u >> 16) & 1u);  // RNE
  return (unsigned short)(r >> 16);
}

__device__ __forceinline__ void async_lds16(const void* g, void* l) {
  __builtin_amdgcn_global_load_lds(
      (const __attribute__((address_space(1))) unsigned int*)g,
      (__attribute__((address_space(3))) unsigned int*)l, 16, 0, 0);
}

// ---------------------------------------------------------------------------
// Prep: build bf16 weights in ws.
//  wsWe: [E][U][F] bf16, with 8-elem (16B) blocks XOR-swizzled: blk' = blk ^ (u&7)
//        (bank-conflict-free ds_read_b128 AND lane-linear for global_load_lds)
//  wsWg: [E][F] bf16 (plain; read directly from global in main kernel)
// ---------------------------------------------------------------------------
__global__ void moe_prep(const float* __restrict__ Wg,
                         const float* __restrict__ We,
                         unsigned short* __restrict__ wsWe,
                         unsigned short* __restrict__ wsWg) {
  int idx = blockIdx.x * 256 + threadIdx.x;
  if (idx < E_DIM * U_DIM * F_DIM) {
    int u = idx & 63;
    int f = (idx >> 6) & 127;
    int e = idx >> 13;
    float v = We[(e << 13) + (f << 6) + u];  // We[e][f][u]; coalesced in u
    int blk = (f >> 3) ^ (u & 7);
    wsWe[(e << 13) + (u << 7) + (blk << 3) + (f & 7)] = f2bf(v);
  } else {
    int j = idx - E_DIM * U_DIM * F_DIM;
    if (j < E_DIM * F_DIM) {
      int e = j >> 7, f = j & 127;
      wsWg[j] = f2bf(Wg[f * E_DIM + e]);  // WgT[e][f]
    }
  }
}

// ---------------------------------------------------------------------------
// Main fused kernel. Grid 256 x 512 threads (8 waves). Tile: 64 tokens.
// Wave tile: 32m x 16u (wid&1 -> m half, wid>>1 -> u column of 16).
// ---------------------------------------------------------------------------
__global__ __launch_bounds__(512, 2) void moe_main(
    const float* __restrict__ x,
    const float* __restrict__ bg,
    const float* __restrict__ be,
    const unsigned short* __restrict__ wsWe,
    const unsigned short* __restrict__ wsWg,
    float* __restrict__ out) {
  __shared__ unsigned short Xs[64 * 136];        // padded rows: +8 bf16
  __shared__ unsigned short WeS[2][64 * 128];    // double-buffered, swizzled

  const int tid  = threadIdx.x;
  const int lane = tid & 63;
  const int wid  = tid >> 6;       // 0..7
  const int quad = lane >> 4;      // 0..3
  const int l15  = lane & 15;
  const int mtop = (wid & 1) * 32; // wave's 32-row half
  const int u    = (wid >> 1) * 16 + l15;  // wave-fixed u column
  const int base = blockIdx.x * MT;

  // ---- issue We[0] prefetch (2 x 1KB chunks per wave) before X staging
  {
    const int c0 = wid * 2;
    const unsigned short* g = wsWe + c0 * 512 + lane * 8;
    async_lds16(g, &WeS[0][c0 * 512]);
    async_lds16(g + 512, &WeS[0][(c0 + 1) * 512]);
  }

  // ---- stage X tile (fp32 -> bf16) into LDS, padded rows
  {
    const int row = tid >> 3;
    const int c8  = tid & 7;  // 16-float group
    const float4* src = (const float4*)(x + (size_t)(base + row) * F_DIM + c8 * 16);
    float4 v0 = src[0], v1 = src[1], v2 = src[2], v3 = src[3];
    union { unsigned short us[16]; uint4 q[2]; } p;
    p.us[0] = f2bf(v0.x); p.us[1] = f2bf(v0.y); p.us[2]  = f2bf(v0.z); p.us[3]  = f2bf(v0.w);
    p.us[4] = f2bf(v1.x); p.us[5] = f2bf(v1.y); p.us[6]  = f2bf(v1.z); p.us[7]  = f2bf(v1.w);
    p.us[8] = f2bf(v2.x); p.us[9] = f2bf(v2.y); p.us[10] = f2bf(v2.z); p.us[11] = f2bf(v2.w);
    p.us[12] = f2bf(v3.x); p.us[13] = f2bf(v3.y); p.us[14] = f2bf(v3.z); p.us[15] = f2bf(v3.w);
    uint4* dst = (uint4*)&Xs[row * 136 + c8 * 16];
    dst[0] = p.q[0];
    dst[1] = p.q[1];
  }
  __syncthreads();  // X ready; implicit vmcnt(0) also lands We[0]

  // ---- preload A fragments (X never re-read from LDS after this)
  bf16x8 a[2][4];
#pragma unroll
  for (int mb = 0; mb < 2; mb++)
#pragma unroll
    for (int ks = 0; ks < 4; ks++)
      a[mb][ks] = *(const bf16x8*)&Xs[(mtop + mb * 16 + l15) * 136 + ks * 32 + quad * 8];

  // ---- gate via MFMA, kept in C-layout registers: gate[m=quad*4+r][e=et*16+l15]
  float gate_reg[2][2][4];  // [mb][et][r]
#pragma unroll
  for (int mb = 0; mb < 2; mb++) {
#pragma unroll
    for (int et = 0; et < 2; et++) {
      floatx4 g = {0.f, 0.f, 0.f, 0.f};
#pragma unroll
      for (int ks = 0; ks < 4; ks++) {
        bf16x8 wb = *(const bf16x8*)&wsWg[((et << 4) + l15) * 128 + ks * 32 + quad * 8];
        g = MFMA16(a[mb][ks], wb, g);
      }
      float bgv = bg[(et << 4) + l15];
#pragma unroll
      for (int r = 0; r < 4; r++) gate_reg[mb][et][r] = g[r] + bgv;
    }
  }

  float oacc[8];
#pragma unroll
  for (int i = 0; i < 8; i++) oacc[i] = 0.f;

  // ---- expert loop: prefetch e+1 right after barrier (full iteration in flight)
#pragma unroll
  for (int half = 0; half < 2; half++) {
    for (int ee = 0; ee < 16; ee++) {
      const int e = (half << 4) | ee;
      __syncthreads();  // implicit vmcnt(0): buf[e&1] complete; buf[(e+1)&1] free
      if (e + 1 < E_DIM) {
        const int c0 = wid * 2;
        const unsigned short* g =
            wsWe + (size_t)(e + 1) * 8192 + c0 * 512 + lane * 8;
        async_lds16(g, &WeS[(e + 1) & 1][c0 * 512]);
        async_lds16(g + 512, &WeS[(e + 1) & 1][(c0 + 1) * 512]);
      }
      const float bev = be[e * U_DIM + u];
      const unsigned short* Wb = WeS[e & 1];
      bf16x8 b[4];
#pragma unroll
      for (int ks = 0; ks < 4; ks++) {
        int blk = ((ks << 2) | quad) ^ (u & 7);
        b[ks] = *(const bf16x8*)&Wb[(u << 7) + (blk << 3)];
      }
      floatx4 h0 = {0.f, 0.f, 0.f, 0.f}, h1 = {0.f, 0.f, 0.f, 0.f};
#pragma unroll
      for (int ks = 0; ks < 4; ks++) h0 = MFMA16(a[0][ks], b[ks], h0);
#pragma unroll
      for (int ks = 0; ks < 4; ks++) h1 = MFMA16(a[1][ks], b[ks], h1);

      const int gsrc = (quad << 4) | ee;  // lane holding gate[.][e]
#pragma unroll
      for (int r = 0; r < 4; r++) {
        float gv0 = __shfl(gate_reg[0][half][r], gsrc);
        float gv1 = __shfl(gate_reg[1][half][r], gsrc);
        float t0 = h0[r] + bev;
        t0 = fmaxf(t0, 0.f) + 0.01f * fminf(t0, 0.f);
        float t1 = h1[r] + bev;
        t1 = fmaxf(t1, 0.f) + 0.01f * fminf(t1, 0.f);
        oacc[r]     = fmaf(gv0, t0, oacc[r]);
        oacc[4 + r] = fmaf(gv1, t1, oacc[4 + r]);
      }
    }
  }

  // ---- store: rows = base+mtop+mb*16+quad*4+r, col = u (16 consecutive per quad)
#pragma unroll
  for (int mb = 0; mb < 2; mb++)
#pragma unroll
    for (int r = 0; r < 4; r++)
      out[(size_t)(base + mtop + mb * 16 + quad * 4 + r) * U_DIM + u] =
          oacc[mb * 4 + r];
}

extern "C" void kernel_launch(void* const* d_in, const int* in_sizes, int n_in,
                              void* d_out, int out_size, void* d_ws, size_t ws_size,
                              hipStream_t stream) {
  const float* x  = (const float*)d_in[0];
  const float* Wg = (const float*)d_in[1];
  const float* bg = (const float*)d_in[2];
  const float* We = (const float*)d_in[3];
  const float* be = (const float*)d_in[4];
  unsigned short* wsWe = (unsigned short*)d_ws;                 // 512 KB
  unsigned short* wsWg = wsWe + E_DIM * U_DIM * F_DIM;          // +8 KB
  (void)in_sizes; (void)n_in; (void)out_size; (void)ws_size;

  moe_prep<<<(E_DIM * U_DIM * F_DIM + E_DIM * F_DIM) / 256, 256, 0, stream>>>(
      Wg, We, wsWe, wsWg);
  moe_main<<<N_TOK / MT, 512, 0, stream>>>(x, bg, be, wsWe, wsWg, (float*)d_out);
}

// Round 2
// 80.757 us; speedup vs baseline: 1.2173x; 1.2173x over previous
//
#include <hip/hip_runtime.h>
#include <stdint.h>

#define N_TOK 16384
#define F_DIM 128
#define U_DIM 64
#define E_DIM 32

typedef __bf16 bf16x8 __attribute__((ext_vector_type(8)));
typedef float  floatx4 __attribute__((ext_vector_type(4)));

#define MFMA16(a, b, c) __builtin_amdgcn_mfma_f32_16x16x32_bf16((a), (b), (c), 0, 0, 0)

__device__ __forceinline__ unsigned short f2bf(float f) {
  union { float f; unsigned u; } v; v.f = f;
  unsigned r = v.u + 0x7FFFu + ((v.u >> 16) & 1u);  // RNE
  return (unsigned short)(r >> 16);
}

// ---------------------------------------------------------------------------
// Prep: fragment-linear bf16 weights in ws. Fully coalesced reads AND writes.
//  wsWe elem idx: ((e*4+ks)*4+quad)*512 + u*8 + j   == We[e][ks*32+quad*8+j][u]
//  wsWg elem idx: ((et*4+ks)*64 + lane)*8 + j       == Wg[ks*32+(lane>>4)*8+j][et*16+(lane&15)]
// ---------------------------------------------------------------------------
__global__ __launch_bounds__(256) void moe_prep(
    const float* __restrict__ Wg, const float* __restrict__ We,
    unsigned short* __restrict__ wsWe, unsigned short* __restrict__ wsWg) {
  int t = blockIdx.x * 256 + threadIdx.x;
  if (t < 32768) {
    int u = t & 63, quad = (t >> 6) & 3, ks = (t >> 8) & 3, e = t >> 10;
    int f0 = ks * 32 + quad * 8;
    const float* src = We + e * 8192 + f0 * 64 + u;  // stride 64 floats in f
    union { unsigned short us[8]; uint4 q; } p;
#pragma unroll
    for (int j = 0; j < 8; j++) p.us[j] = f2bf(src[j * 64]);
    *(uint4*)(wsWe + t * 8) = p.q;                   // 16B coalesced store
  } else if (t < 32768 + 512) {
    int t2 = t - 32768;
    int l15 = t2 & 15, quad = (t2 >> 4) & 3, ks = (t2 >> 6) & 3, et = t2 >> 8;
    int e = et * 16 + l15, f0 = ks * 32 + quad * 8;
    union { unsigned short us[8]; uint4 q; } p;
#pragma unroll
    for (int j = 0; j < 8; j++) p.us[j] = f2bf(Wg[(f0 + j) * 32 + e]);
    *(uint4*)(wsWg + t2 * 8) = p.q;
  }
}

// ---------------------------------------------------------------------------
// Main: 256 wgs x 256 thr (4 waves). Wave tile 64m x 16u (u-col = wid).
// B-frags streamed from L2 into registers, depth-2 pipeline; 2 barriers total.
// ---------------------------------------------------------------------------
__global__ __launch_bounds__(256, 1) void moe_main(
    const float* __restrict__ x,
    const float* __restrict__ bg,
    const float* __restrict__ be,
    const unsigned short* __restrict__ wsWe,
    const unsigned short* __restrict__ wsWg,
    float* __restrict__ out) {
  __shared__ unsigned short Xs[64 * 136];  // padded rows
  __shared__ float Gs[E_DIM][68];          // gate [e][row], padded

  const int tid  = threadIdx.x;
  const int lane = tid & 63;
  const int wid  = tid >> 6;       // 0..3
  const int quad = lane >> 4;
  const int l15  = lane & 15;
  const int u    = wid * 16 + l15;
  const int base = blockIdx.x * 64;

  // ---- prefetch B for e=0,1 (L2) before anything else
  bf16x8 bbuf[2][4];
  float bevb[2];
#pragma unroll
  for (int ks = 0; ks < 4; ks++)
    bbuf[0][ks] = *(const bf16x8*)(wsWe + (size_t)((0 * 4 + ks) * 4 + quad) * 512 + u * 8);
#pragma unroll
  for (int ks = 0; ks < 4; ks++)
    bbuf[1][ks] = *(const bf16x8*)(wsWe + (size_t)((1 * 4 + ks) * 4 + quad) * 512 + u * 8);
  bevb[0] = be[u];
  bevb[1] = be[U_DIM + u];

  // ---- stage X tile (fp32 -> bf16) into LDS
#pragma unroll
  for (int p = 0; p < 2; p++) {
    const int row = p * 32 + (tid >> 3);
    const int c16 = tid & 7;
    const float4* src = (const float4*)(x + (size_t)(base + row) * F_DIM + c16 * 16);
    float4 v0 = src[0], v1 = src[1], v2 = src[2], v3 = src[3];
    union { unsigned short us[16]; uint4 q[2]; } pk;
    pk.us[0]  = f2bf(v0.x); pk.us[1]  = f2bf(v0.y); pk.us[2]  = f2bf(v0.z); pk.us[3]  = f2bf(v0.w);
    pk.us[4]  = f2bf(v1.x); pk.us[5]  = f2bf(v1.y); pk.us[6]  = f2bf(v1.z); pk.us[7]  = f2bf(v1.w);
    pk.us[8]  = f2bf(v2.x); pk.us[9]  = f2bf(v2.y); pk.us[10] = f2bf(v2.z); pk.us[11] = f2bf(v2.w);
    pk.us[12] = f2bf(v3.x); pk.us[13] = f2bf(v3.y); pk.us[14] = f2bf(v3.z); pk.us[15] = f2bf(v3.w);
    uint4* dst = (uint4*)&Xs[row * 136 + c16 * 16];
    dst[0] = pk.q[0];
    dst[1] = pk.q[1];
  }
  __syncthreads();  // barrier 1: X ready

  // ---- gate: wave wid computes rows [wid*16, wid*16+16), writes to Gs
  {
    bf16x8 ag[4];
#pragma unroll
    for (int ks = 0; ks < 4; ks++)
      ag[ks] = *(const bf16x8*)&Xs[(wid * 16 + l15) * 136 + ks * 32 + quad * 8];
#pragma unroll
    for (int et = 0; et < 2; et++) {
      floatx4 g = {0.f, 0.f, 0.f, 0.f};
#pragma unroll
      for (int ks = 0; ks < 4; ks++) {
        bf16x8 wb = *(const bf16x8*)(wsWg + (size_t)((et * 4 + ks) * 64 + lane) * 8);
        g = MFMA16(ag[ks], wb, g);
      }
      float bgv = bg[et * 16 + l15];
#pragma unroll
      for (int r = 0; r < 4; r++)
        Gs[et * 16 + l15][wid * 16 + quad * 4 + r] = g[r] + bgv;
    }
  }

  // ---- preload all A fragments (64 rows)
  bf16x8 a[4][4];
#pragma unroll
  for (int mb = 0; mb < 4; mb++)
#pragma unroll
    for (int ks = 0; ks < 4; ks++)
      a[mb][ks] = *(const bf16x8*)&Xs[(mb * 16 + l15) * 136 + ks * 32 + quad * 8];
  __syncthreads();  // barrier 2: Gs ready (last barrier)

  float oacc[16];
#pragma unroll
  for (int i = 0; i < 16; i++) oacc[i] = 0.f;

  // ---- expert loop: no barriers; B depth-2 register pipeline
#pragma unroll 2
  for (int e = 0; e < E_DIM; ++e) {
    const int c = e & 1;
    // gate broadcast reads (issued early; hidden under MFMA issue)
    float g[16];
#pragma unroll
    for (int mb = 0; mb < 4; mb++)
#pragma unroll
      for (int r = 0; r < 4; r++)
        g[mb * 4 + r] = Gs[e][mb * 16 + quad * 4 + r];

    const float bev = bevb[c];
    floatx4 h[4];
#pragma unroll
    for (int mb = 0; mb < 4; mb++) h[mb] = {bev, bev, bev, bev};
#pragma unroll
    for (int ks = 0; ks < 4; ks++)
#pragma unroll
      for (int mb = 0; mb < 4; mb++)
        h[mb] = MFMA16(a[mb][ks], bbuf[c][ks], h[mb]);

    // prefetch e+2 into the buffer just consumed
    if (e + 2 < E_DIM) {
#pragma unroll
      for (int ks = 0; ks < 4; ks++)
        bbuf[c][ks] = *(const bf16x8*)(wsWe + (size_t)(((e + 2) * 4 + ks) * 4 + quad) * 512 + u * 8);
      bevb[c] = be[(e + 2) * U_DIM + u];
    }

    // epilogue: leaky = max(t, 0.01t); out += gate * leaky(h)
#pragma unroll
    for (int mb = 0; mb < 4; mb++)
#pragma unroll
      for (int r = 0; r < 4; r++) {
        float t = h[mb][r];
        t = fmaxf(t, 0.01f * t);
        oacc[mb * 4 + r] = fmaf(g[mb * 4 + r], t, oacc[mb * 4 + r]);
      }
  }

  // ---- store
#pragma unroll
  for (int mb = 0; mb < 4; mb++)
#pragma unroll
    for (int r = 0; r < 4; r++)
      out[(size_t)(base + mb * 16 + quad * 4 + r) * U_DIM + u] = oacc[mb * 4 + r];
}

extern "C" void kernel_launch(void* const* d_in, const int* in_sizes, int n_in,
                              void* d_out, int out_size, void* d_ws, size_t ws_size,
                              hipStream_t stream) {
  const float* x  = (const float*)d_in[0];
  const float* Wg = (const float*)d_in[1];
  const float* bg = (const float*)d_in[2];
  const float* We = (const float*)d_in[3];
  const float* be = (const float*)d_in[4];
  unsigned short* wsWe = (unsigned short*)d_ws;              // 512 KB
  unsigned short* wsWg = wsWe + E_DIM * U_DIM * F_DIM;       // +8 KB
  (void)in_sizes; (void)n_in; (void)out_size; (void)ws_size;

  moe_prep<<<130, 256, 0, stream>>>(Wg, We, wsWe, wsWg);
  moe_main<<<N_TOK / 64, 256, 0, stream>>>(x, bg, be, wsWe, wsWg, (float*)d_out);
}

// Round 3
// 79.763 us; speedup vs baseline: 1.2324x; 1.0125x over previous
//
#include <hip/hip_runtime.h>
#include <stdint.h>

#define N_TOK 16384
#define F_DIM 128
#define U_DIM 64
#define E_DIM 32

typedef __bf16 bf16x8 __attribute__((ext_vector_type(8)));
typedef float  floatx4 __attribute__((ext_vector_type(4)));

#define MFMA16(a, b, c) __builtin_amdgcn_mfma_f32_16x16x32_bf16((a), (b), (c), 0, 0, 0)

__device__ __forceinline__ unsigned short f2bf(float f) {
  union { float f; unsigned u; } v; v.f = f;
  unsigned r = v.u + 0x7FFFu + ((v.u >> 16) & 1u);  // RNE
  return (unsigned short)(r >> 16);
}

// ---------------------------------------------------------------------------
// Prep: fragment-linear bf16 weights in ws. Coalesced reads (u == lane is the
// fastest dim of We) and 16B coalesced stores.
//  wsWe elem idx: ((e*4+ks)*4+quad)*512 + u*8 + j   == We[e][ks*32+quad*8+j][u]
//  wsWg elem idx: ((et*4+ks)*64 + lane)*8 + j       == Wg[ks*32+(lane>>4)*8+j][et*16+(lane&15)]
// ---------------------------------------------------------------------------
__global__ __launch_bounds__(256) void moe_prep(
    const float* __restrict__ Wg, const float* __restrict__ We,
    unsigned short* __restrict__ wsWe, unsigned short* __restrict__ wsWg) {
  int t = blockIdx.x * 256 + threadIdx.x;
  if (t < 32768) {
    int u = t & 63, quad = (t >> 6) & 3, ks = (t >> 8) & 3, e = t >> 10;
    int f0 = ks * 32 + quad * 8;
    const float* src = We + e * 8192 + f0 * 64 + u;  // wave reads full 256B rows
    union { unsigned short us[8]; uint4 q; } p;
#pragma unroll
    for (int j = 0; j < 8; j++) p.us[j] = f2bf(src[j * 64]);
    *(uint4*)(wsWe + t * 8) = p.q;
  } else if (t < 32768 + 512) {
    int t2 = t - 32768;
    int l15 = t2 & 15, quad = (t2 >> 4) & 3, ks = (t2 >> 6) & 3, et = t2 >> 8;
    int e = et * 16 + l15, f0 = ks * 32 + quad * 8;
    union { unsigned short us[8]; uint4 q; } p;
#pragma unroll
    for (int j = 0; j < 8; j++) p.us[j] = f2bf(Wg[(f0 + j) * 32 + e]);
    *(uint4*)(wsWg + t2 * 8) = p.q;
  }
}

// ---------------------------------------------------------------------------
// Main: 256 wgs x 256 thr (4 waves, 1/SIMD). Wave tile 64m x 16u (u-col=wid).
// B streamed from L2 via a depth-4 register ring (prefetch e+3 at loop top —
// ~3 iterations ≈ 300+ cyc in flight, covers L2 latency at 1 wave/SIMD).
// Gate rows read as ds_read_b128, double-buffered one expert ahead.
// 2 barriers total.
// ---------------------------------------------------------------------------
__global__ __launch_bounds__(256, 1) void moe_main(
    const float* __restrict__ x,
    const float* __restrict__ bg,
    const float* __restrict__ be,
    const unsigned short* __restrict__ wsWe,
    const unsigned short* __restrict__ wsWg,
    float* __restrict__ out) {
  __shared__ unsigned short Xs[64 * 136];  // padded rows
  __shared__ float Gs[E_DIM][68];          // gate [e][row], padded (272B rows, 16B-aligned)

  const int tid  = threadIdx.x;
  const int lane = tid & 63;
  const int wid  = tid >> 6;       // 0..3
  const int quad = lane >> 4;
  const int l15  = lane & 15;
  const int u    = wid * 16 + l15;
  const int base = blockIdx.x * 64;

  // ---- B ring: prefetch experts 0..2 (L2) before anything else
  bf16x8 bbuf[4][4];
  float bevb[4];
#pragma unroll
  for (int e0 = 0; e0 < 3; e0++) {
#pragma unroll
    for (int ks = 0; ks < 4; ks++)
      bbuf[e0][ks] = *(const bf16x8*)(wsWe + (size_t)((e0 * 4 + ks) * 4 + quad) * 512 + u * 8);
    bevb[e0] = be[e0 * U_DIM + u];
  }

  // ---- stage X tile (fp32 -> bf16) into LDS
#pragma unroll
  for (int p = 0; p < 2; p++) {
    const int row = p * 32 + (tid >> 3);
    const int c16 = tid & 7;
    const float4* src = (const float4*)(x + (size_t)(base + row) * F_DIM + c16 * 16);
    float4 v0 = src[0], v1 = src[1], v2 = src[2], v3 = src[3];
    union { unsigned short us[16]; uint4 q[2]; } pk;
    pk.us[0]  = f2bf(v0.x); pk.us[1]  = f2bf(v0.y); pk.us[2]  = f2bf(v0.z); pk.us[3]  = f2bf(v0.w);
    pk.us[4]  = f2bf(v1.x); pk.us[5]  = f2bf(v1.y); pk.us[6]  = f2bf(v1.z); pk.us[7]  = f2bf(v1.w);
    pk.us[8]  = f2bf(v2.x); pk.us[9]  = f2bf(v2.y); pk.us[10] = f2bf(v2.z); pk.us[11] = f2bf(v2.w);
    pk.us[12] = f2bf(v3.x); pk.us[13] = f2bf(v3.y); pk.us[14] = f2bf(v3.z); pk.us[15] = f2bf(v3.w);
    uint4* dst = (uint4*)&Xs[row * 136 + c16 * 16];
    dst[0] = pk.q[0];
    dst[1] = pk.q[1];
  }
  __syncthreads();  // barrier 1: X ready

  // ---- gate: wave wid computes rows [wid*16, wid*16+16), writes to Gs
  {
    bf16x8 ag[4];
#pragma unroll
    for (int ks = 0; ks < 4; ks++)
      ag[ks] = *(const bf16x8*)&Xs[(wid * 16 + l15) * 136 + ks * 32 + quad * 8];
#pragma unroll
    for (int et = 0; et < 2; et++) {
      floatx4 g = {0.f, 0.f, 0.f, 0.f};
#pragma unroll
      for (int ks = 0; ks < 4; ks++) {
        bf16x8 wb = *(const bf16x8*)(wsWg + (size_t)((et * 4 + ks) * 64 + lane) * 8);
        g = MFMA16(ag[ks], wb, g);
      }
      float bgv = bg[et * 16 + l15];
#pragma unroll
      for (int r = 0; r < 4; r++)
        Gs[et * 16 + l15][wid * 16 + quad * 4 + r] = g[r] + bgv;
    }
  }

  // ---- preload all A fragments (64 rows; X never re-read after this)
  bf16x8 a[4][4];
#pragma unroll
  for (int mb = 0; mb < 4; mb++)
#pragma unroll
    for (int ks = 0; ks < 4; ks++)
      a[mb][ks] = *(const bf16x8*)&Xs[(mb * 16 + l15) * 136 + ks * 32 + quad * 8];
  __syncthreads();  // barrier 2: Gs ready (last barrier)

  float oacc[16];
#pragma unroll
  for (int i = 0; i < 16; i++) oacc[i] = 0.f;

  // ---- gate double-buffer: preload e=0 as float4 rows
  float4 gbuf[2][4];
#pragma unroll
  for (int mb = 0; mb < 4; mb++)
    gbuf[0][mb] = *(const float4*)&Gs[0][mb * 16 + quad * 4];

  // ---- expert loop: no barriers
#pragma unroll 4
  for (int e = 0; e < E_DIM; ++e) {
    const int c = e & 3;
    const int gp = e & 1;

    // prefetch B for e+3 into the slot last used by e-1 (consumed)
    if (e + 3 < E_DIM) {
#pragma unroll
      for (int ks = 0; ks < 4; ks++)
        bbuf[(e + 3) & 3][ks] =
            *(const bf16x8*)(wsWe + (size_t)(((e + 3) * 4 + ks) * 4 + quad) * 512 + u * 8);
      bevb[(e + 3) & 3] = be[(e + 3) * U_DIM + u];
    }
    // prefetch gate rows for e+1 (ds_read_b128 x4, hidden under e's MFMAs)
    if (e + 1 < E_DIM) {
#pragma unroll
      for (int mb = 0; mb < 4; mb++)
        gbuf[gp ^ 1][mb] = *(const float4*)&Gs[e + 1][mb * 16 + quad * 4];
    }

    const float bev = bevb[c];
    floatx4 h[4];
#pragma unroll
    for (int mb = 0; mb < 4; mb++) h[mb] = {bev, bev, bev, bev};
#pragma unroll
    for (int ks = 0; ks < 4; ks++)
#pragma unroll
      for (int mb = 0; mb < 4; mb++)
        h[mb] = MFMA16(a[mb][ks], bbuf[c][ks], h[mb]);

    // epilogue: out += gate * leaky(h),  leaky(t) = max(t, 0.01t)
#pragma unroll
    for (int mb = 0; mb < 4; mb++) {
      const float4 g4 = gbuf[gp][mb];
      const float gr[4] = {g4.x, g4.y, g4.z, g4.w};
#pragma unroll
      for (int r = 0; r < 4; r++) {
        float t = h[mb][r];
        t = fmaxf(t, 0.01f * t);
        oacc[mb * 4 + r] = fmaf(gr[r], t, oacc[mb * 4 + r]);
      }
    }
  }

  // ---- store
#pragma unroll
  for (int mb = 0; mb < 4; mb++)
#pragma unroll
    for (int r = 0; r < 4; r++)
      out[(size_t)(base + mb * 16 + quad * 4 + r) * U_DIM + u] = oacc[mb * 4 + r];
}

extern "C" void kernel_launch(void* const* d_in, const int* in_sizes, int n_in,
                              void* d_out, int out_size, void* d_ws, size_t ws_size,
                              hipStream_t stream) {
  const float* x  = (const float*)d_in[0];
  const float* Wg = (const float*)d_in[1];
  const float* bg = (const float*)d_in[2];
  const float* We = (const float*)d_in[3];
  const float* be = (const float*)d_in[4];
  unsigned short* wsWe = (unsigned short*)d_ws;              // 512 KB
  unsigned short* wsWg = wsWe + E_DIM * U_DIM * F_DIM;       // +8 KB
  (void)in_sizes; (void)n_in; (void)out_size; (void)ws_size;

  moe_prep<<<130, 256, 0, stream>>>(Wg, We, wsWe, wsWg);
  moe_main<<<N_TOK / 64, 256, 0, stream>>>(x, bg, be, wsWe, wsWg, (float*)d_out);
}